// Round 5
// baseline (148.992 us; speedup 1.0000x reference)
//
#include <hip/hip_runtime.h>
#include <math.h>

// MoE top-2: S=1, B=32, H=4096, E=8.
// out[b][d] = sum_{e in top2(b)} wt[b][e] * sum_h x[b][h] * expert_w[e][h][d]
// Memory-bound: expert_w = 537 MB read once ~ 85 us @ 6.3 TB/s.
// R5: prefetch depth 2 -> 4. In-flight bytes/CU was the binding constraint
//     (32 KB @ ~1800cy loaded latency = 5.2 TB/s observed); 64 KB removes it.

constexpr int HD = 4096;
constexpr int NE = 8;
constexpr int NB = 32;
constexpr int TSLOT = 16;          // token slots per pass
constexpr int MAXTOK = 32;
constexpr int NH = 32;             // h segments
constexpr int HSEG = HD / NH;      // 128
constexpr int ND = 4;              // d chunks
constexpr int DCHUNK = HD / ND;    // 1024 floats
constexpr int NPART = 2 * NH;      // 64 partial planes per token

// ---- routing: 1 block per token: logits -> top-2 -------------------------
__global__ __launch_bounds__(256) void route_kernel(
    const float* __restrict__ x, const float* __restrict__ gw,
    int* __restrict__ re0, int* __restrict__ re1, float* __restrict__ rpre)
{
    const int b = blockIdx.x;
    const int tid = threadIdx.x;
    __shared__ float xrow[HD];

    const float4* xsrc = (const float4*)(x + (size_t)b * HD);
    #pragma unroll
    for (int i = 0; i < HD / 4 / 256; ++i) {
        int idx = i * 256 + tid;
        ((float4*)xrow)[idx] = xsrc[idx];
    }
    __syncthreads();

    const int e = tid & 7, hg = tid >> 3;
    float acc = 0.f;
    #pragma unroll 8
    for (int i = 0; i < HD / 32; ++i) {
        int h = hg + 32 * i;
        acc += xrow[h] * gw[h * NE + e];
    }
    __shared__ float part[32][NE];
    part[hg][e] = acc;
    __syncthreads();
    if (tid < NE) {
        float s = 0.f;
        #pragma unroll
        for (int i = 0; i < 32; ++i) s += part[i][tid];
        part[0][tid] = s;
    }
    __syncthreads();
    if (tid == 0) {
        float w0 = -3.4e38f; int e0 = 0;
        #pragma unroll
        for (int i = 0; i < NE; ++i) { float v = part[0][i]; if (v > w0) { w0 = v; e0 = i; } }
        float w1 = -3.4e38f; int e1 = 0;
        #pragma unroll
        for (int i = 0; i < NE; ++i) { if (i == e0) continue; float v = part[0][i]; if (v > w1) { w1 = v; e1 = i; } }
        float pre = 1.0f / (1.0f + expf(w1 - w0));
        re0[b] = e0; re1[b] = e1; rpre[b] = pre;
    }
}

// ---- grouped GEMV: block = (hseg, dchunk, e); all tokens of e ------------
__global__ __launch_bounds__(256, 4) void moe_gemv_kernel(
    const float* __restrict__ x, const float* __restrict__ ew,
    const int* __restrict__ re0, const int* __restrict__ re1,
    const float* __restrict__ rpre, float* __restrict__ part)
{
    const int hseg = blockIdx.x;        // 32
    const int dchunk = blockIdx.y;      // 4
    const int e = blockIdx.z;           // 8
    const int tid = threadIdx.x;

    __shared__ int   stok[MAXTOK];
    __shared__ int   sslt[MAXTOK];
    __shared__ float swt[MAXTOK];
    __shared__ int   snt;

    if (tid == 0) {
        int c = 0;
        for (int b = 0; b < NB; ++b) {
            int r0 = re0[b]; int r1 = re1[b]; float p = rpre[b];
            if (r0 == e)      { stok[c] = b; swt[c] = p;       sslt[c] = 0; ++c; }
            else if (r1 == e) { stok[c] = b; swt[c] = 1.f - p; sslt[c] = 1; ++c; }
        }
        snt = c;
        int cp = (c + TSLOT - 1) & ~(TSLOT - 1);
        for (int s = c; s < cp; ++s) { stok[s] = 0; swt[s] = 0.f; sslt[s] = 0; }
    }
    __syncthreads();
    const int nt = snt;
    if (nt == 0) return;
    const int npass = (nt + TSLOT - 1) / TSLOT;

    __shared__ float xs[HSEG][TSLOT];   // 8 KB, pre-scaled x
    const int h0 = hseg * HSEG;
    const int d0 = dchunk * DCHUNK + tid * 4;

    for (int p = 0; p < npass; ++p) {
        __syncthreads();
        {
            const int t = tid & 15, hb = tid >> 4;
            const int s = p * TSLOT + t;
            const int tok = stok[s]; const float wt = swt[s];
            const float* xp = x + (size_t)tok * HD + h0 + hb * 8;
            #pragma unroll
            for (int it = 0; it < 2; ++it) {
                float4 v = *(const float4*)(xp + it * 4);
                int h = hb * 8 + it * 4;
                xs[h + 0][t] = wt * v.x; xs[h + 1][t] = wt * v.y;
                xs[h + 2][t] = wt * v.z; xs[h + 3][t] = wt * v.w;
            }
        }
        __syncthreads();

        const float* wp = ew + (size_t)e * HD * HD + (size_t)h0 * HD + d0;

        float4 acc[TSLOT];              // 64 VGPRs
        #pragma unroll
        for (int t = 0; t < TSLOT; ++t) acc[t] = make_float4(0.f, 0.f, 0.f, 0.f);

        auto compute = [&](int h, const float4& wv) {
            #pragma unroll
            for (int q = 0; q < 4; ++q) {
                float4 xv = ((const float4*)(&xs[h][0]))[q];   // broadcast b128
                acc[q*4+0].x += xv.x * wv.x; acc[q*4+0].y += xv.x * wv.y;
                acc[q*4+0].z += xv.x * wv.z; acc[q*4+0].w += xv.x * wv.w;
                acc[q*4+1].x += xv.y * wv.x; acc[q*4+1].y += xv.y * wv.y;
                acc[q*4+1].z += xv.y * wv.z; acc[q*4+1].w += xv.y * wv.w;
                acc[q*4+2].x += xv.z * wv.x; acc[q*4+2].y += xv.z * wv.y;
                acc[q*4+2].z += xv.z * wv.z; acc[q*4+2].w += xv.z * wv.w;
                acc[q*4+3].x += xv.w * wv.x; acc[q*4+3].y += xv.w * wv.y;
                acc[q*4+3].z += xv.w * wv.z; acc[q*4+3].w += xv.w * wv.w;
            }
        };

        // 4-row software prefetch: 4 KB/lane-group in flight during FMAs
        float4 wv0 = *(const float4*)wp;
        float4 wv1 = *(const float4*)(wp + HD);
        float4 wv2 = *(const float4*)(wp + 2 * HD);
        float4 wv3 = *(const float4*)(wp + 3 * HD);
        wp += 4 * HD;
        for (int h = 0; h < HSEG - 4; h += 4) {
            float4 n0 = *(const float4*)wp;
            float4 n1 = *(const float4*)(wp + HD);
            float4 n2 = *(const float4*)(wp + 2 * HD);
            float4 n3 = *(const float4*)(wp + 3 * HD);
            wp += 4 * HD;
            compute(h + 0, wv0);
            compute(h + 1, wv1);
            compute(h + 2, wv2);
            compute(h + 3, wv3);
            wv0 = n0; wv1 = n1; wv2 = n2; wv3 = n3;
        }
        compute(HSEG - 4, wv0);
        compute(HSEG - 3, wv1);
        compute(HSEG - 2, wv2);
        compute(HSEG - 1, wv3);

        // plain coalesced stores to partial planes (no atomics)
        #pragma unroll
        for (int t = 0; t < TSLOT; ++t) {
            const int s = p * TSLOT + t;
            if (s < nt) {
                float* pp = part + ((size_t)(sslt[s] * NH + hseg) * NB + stok[s]) * HD + d0;
                *(float4*)pp = acc[t];
            }
        }
    }
}

// ---- reduce: out[b][d] = sum over 64 partial planes ----------------------
__global__ __launch_bounds__(256) void reduce_kernel(
    const float* __restrict__ part, float* __restrict__ out)
{
    const int idx = blockIdx.x * 256 + threadIdx.x;    // float4 index, 32768
    const float4* p4 = (const float4*)part;
    constexpr int PSTRIDE = NB * HD / 4;
    float4 s = make_float4(0.f, 0.f, 0.f, 0.f);
    #pragma unroll 8
    for (int j = 0; j < NPART; ++j) {
        float4 v = p4[(size_t)j * PSTRIDE + idx];
        s.x += v.x; s.y += v.y; s.z += v.z; s.w += v.w;
    }
    ((float4*)out)[idx] = s;
}

extern "C" void kernel_launch(void* const* d_in, const int* in_sizes, int n_in,
                              void* d_out, int out_size, void* d_ws, size_t ws_size,
                              hipStream_t stream) {
    const float* x  = (const float*)d_in[0];   // [1,1,32,4096]
    const float* gw = (const float*)d_in[1];   // [4096,8]
    const float* ew = (const float*)d_in[2];   // [8,4096,4096]
    float* out = (float*)d_out;                // [1,1,32,4096] fp32

    int*   re0  = (int*)d_ws;
    int*   re1  = re0 + NB;
    float* rpre = (float*)(re1 + NB);
    float* partb = (float*)((char*)d_ws + 512);            // 64*32*4096 f32 = 32 MB

    route_kernel<<<NB, 256, 0, stream>>>(x, gw, re0, re1, rpre);
    dim3 grid(NH, ND, NE);
    moe_gemv_kernel<<<grid, 256, 0, stream>>>(x, ew, re0, re1, rpre, partb);
    reduce_kernel<<<NB * HD / 4 / 256, 256, 0, stream>>>(partb, out);
}

// Round 7
// 106.056 us; speedup vs baseline: 1.4048x; 1.4048x over previous
//
#include <hip/hip_runtime.h>
#include <math.h>

// MoE top-2: S=1, B=32, H=4096, E=8.
// out[b][d] = sum_{e in top2(b)} wt[b][e] * sum_h x[b][h] * expert_w[e][h][d]
// Memory-bound: expert_w = 537 MB read once.
// R7: R6 retry — __builtin_nontemporal_load needs ext_vector_type, not
//     HIP_vector_type. Same plan: NT loads on streamed-once data (W,
//     partials) + all-CU reduce; GEMV core = proven R4 depth-2.

constexpr int HD = 4096;
constexpr int NE = 8;
constexpr int NB = 32;
constexpr int TSLOT = 16;          // token slots per pass
constexpr int MAXTOK = 32;
constexpr int NH = 32;             // h segments
constexpr int HSEG = HD / NH;      // 128
constexpr int ND = 4;              // d chunks
constexpr int DCHUNK = HD / ND;    // 1024 floats
constexpr int NPART = 2 * NH;      // 64 partial planes per token

typedef float floatx4 __attribute__((ext_vector_type(4)));

__device__ __forceinline__ float4 nt_load4(const float* p) {
    floatx4 v = __builtin_nontemporal_load((const floatx4*)p);
    return make_float4(v.x, v.y, v.z, v.w);
}

// ---- routing: 1 block per token: logits -> top-2 -------------------------
__global__ __launch_bounds__(256) void route_kernel(
    const float* __restrict__ x, const float* __restrict__ gw,
    int* __restrict__ re0, int* __restrict__ re1, float* __restrict__ rpre)
{
    const int b = blockIdx.x;
    const int tid = threadIdx.x;
    __shared__ float xrow[HD];

    const float4* xsrc = (const float4*)(x + (size_t)b * HD);
    #pragma unroll
    for (int i = 0; i < HD / 4 / 256; ++i) {
        int idx = i * 256 + tid;
        ((float4*)xrow)[idx] = xsrc[idx];
    }
    __syncthreads();

    const int e = tid & 7, hg = tid >> 3;
    float acc = 0.f;
    #pragma unroll 8
    for (int i = 0; i < HD / 32; ++i) {
        int h = hg + 32 * i;
        acc += xrow[h] * gw[h * NE + e];
    }
    __shared__ float part[32][NE];
    part[hg][e] = acc;
    __syncthreads();
    if (tid < NE) {
        float s = 0.f;
        #pragma unroll
        for (int i = 0; i < 32; ++i) s += part[i][tid];
        part[0][tid] = s;
    }
    __syncthreads();
    if (tid == 0) {
        float w0 = -3.4e38f; int e0 = 0;
        #pragma unroll
        for (int i = 0; i < NE; ++i) { float v = part[0][i]; if (v > w0) { w0 = v; e0 = i; } }
        float w1 = -3.4e38f; int e1 = 0;
        #pragma unroll
        for (int i = 0; i < NE; ++i) { if (i == e0) continue; float v = part[0][i]; if (v > w1) { w1 = v; e1 = i; } }
        float pre = 1.0f / (1.0f + expf(w1 - w0));
        re0[b] = e0; re1[b] = e1; rpre[b] = pre;
    }
}

// ---- grouped GEMV: block = (hseg, dchunk, e); all tokens of e ------------
__global__ __launch_bounds__(256, 4) void moe_gemv_kernel(
    const float* __restrict__ x, const float* __restrict__ ew,
    const int* __restrict__ re0, const int* __restrict__ re1,
    const float* __restrict__ rpre, float* __restrict__ part)
{
    const int hseg = blockIdx.x;        // 32
    const int dchunk = blockIdx.y;      // 4
    const int e = blockIdx.z;           // 8
    const int tid = threadIdx.x;

    __shared__ int   stok[MAXTOK];
    __shared__ int   sslt[MAXTOK];
    __shared__ float swt[MAXTOK];
    __shared__ int   snt;

    if (tid == 0) {
        int c = 0;
        for (int b = 0; b < NB; ++b) {
            int r0 = re0[b]; int r1 = re1[b]; float p = rpre[b];
            if (r0 == e)      { stok[c] = b; swt[c] = p;       sslt[c] = 0; ++c; }
            else if (r1 == e) { stok[c] = b; swt[c] = 1.f - p; sslt[c] = 1; ++c; }
        }
        snt = c;
        int cp = (c + TSLOT - 1) & ~(TSLOT - 1);
        for (int s = c; s < cp; ++s) { stok[s] = 0; swt[s] = 0.f; sslt[s] = 0; }
    }
    __syncthreads();
    const int nt = snt;
    if (nt == 0) return;
    const int npass = (nt + TSLOT - 1) / TSLOT;

    __shared__ float xs[HSEG][TSLOT];   // 8 KB, pre-scaled x
    const int h0 = hseg * HSEG;
    const int d0 = dchunk * DCHUNK + tid * 4;

    for (int p = 0; p < npass; ++p) {
        __syncthreads();
        {
            const int t = tid & 15, hb = tid >> 4;
            const int s = p * TSLOT + t;
            const int tok = stok[s]; const float wt = swt[s];
            const float* xp = x + (size_t)tok * HD + h0 + hb * 8;
            #pragma unroll
            for (int it = 0; it < 2; ++it) {
                float4 v = *(const float4*)(xp + it * 4);
                int h = hb * 8 + it * 4;
                xs[h + 0][t] = wt * v.x; xs[h + 1][t] = wt * v.y;
                xs[h + 2][t] = wt * v.z; xs[h + 3][t] = wt * v.w;
            }
        }
        __syncthreads();

        const float* wp = ew + (size_t)e * HD * HD + (size_t)h0 * HD + d0;

        float4 acc[TSLOT];              // 64 VGPRs
        #pragma unroll
        for (int t = 0; t < TSLOT; ++t) acc[t] = make_float4(0.f, 0.f, 0.f, 0.f);

        auto compute = [&](int h, const float4& wv) {
            #pragma unroll
            for (int q = 0; q < 4; ++q) {
                float4 xv = ((const float4*)(&xs[h][0]))[q];   // broadcast b128
                acc[q*4+0].x += xv.x * wv.x; acc[q*4+0].y += xv.x * wv.y;
                acc[q*4+0].z += xv.x * wv.z; acc[q*4+0].w += xv.x * wv.w;
                acc[q*4+1].x += xv.y * wv.x; acc[q*4+1].y += xv.y * wv.y;
                acc[q*4+1].z += xv.y * wv.z; acc[q*4+1].w += xv.y * wv.w;
                acc[q*4+2].x += xv.z * wv.x; acc[q*4+2].y += xv.z * wv.y;
                acc[q*4+2].z += xv.z * wv.z; acc[q*4+2].w += xv.z * wv.w;
                acc[q*4+3].x += xv.w * wv.x; acc[q*4+3].y += xv.w * wv.y;
                acc[q*4+3].z += xv.w * wv.z; acc[q*4+3].w += xv.w * wv.w;
            }
        };

        // 2-row software prefetch (R4 proven best); W read once -> nontemporal
        float4 wv0 = nt_load4(wp);
        float4 wv1 = nt_load4(wp + HD);
        wp += 2 * HD;
        for (int h = 0; h < HSEG - 2; h += 2) {
            float4 n0 = nt_load4(wp);
            float4 n1 = nt_load4(wp + HD);
            wp += 2 * HD;
            compute(h, wv0);
            compute(h + 1, wv1);
            wv0 = n0; wv1 = n1;
        }
        compute(HSEG - 2, wv0);
        compute(HSEG - 1, wv1);

        // plain coalesced stores to partial planes (no atomics)
        #pragma unroll
        for (int t = 0; t < TSLOT; ++t) {
            const int s = p * TSLOT + t;
            if (s < nt) {
                float* pp = part + ((size_t)(sslt[s] * NH + hseg) * NB + stok[s]) * HD + d0;
                *(float4*)pp = acc[t];
            }
        }
    }
}

// ---- reduce: out[b][d] = sum over 64 partial planes ----------------------
__global__ __launch_bounds__(128) void reduce_kernel(
    const float* __restrict__ part, float* __restrict__ out)
{
    const int idx = blockIdx.x * 128 + threadIdx.x;    // float4 index, 32768
    constexpr int PSTRIDE = NB * HD / 4;
    float4 s = make_float4(0.f, 0.f, 0.f, 0.f);
    #pragma unroll 8
    for (int j = 0; j < NPART; ++j) {
        float4 v = nt_load4(part + ((size_t)j * PSTRIDE + idx) * 4);
        s.x += v.x; s.y += v.y; s.z += v.z; s.w += v.w;
    }
    ((float4*)out)[idx] = s;
}

extern "C" void kernel_launch(void* const* d_in, const int* in_sizes, int n_in,
                              void* d_out, int out_size, void* d_ws, size_t ws_size,
                              hipStream_t stream) {
    const float* x  = (const float*)d_in[0];   // [1,1,32,4096]
    const float* gw = (const float*)d_in[1];   // [4096,8]
    const float* ew = (const float*)d_in[2];   // [8,4096,4096]
    float* out = (float*)d_out;                // [1,1,32,4096] fp32

    int*   re0  = (int*)d_ws;
    int*   re1  = re0 + NB;
    float* rpre = (float*)(re1 + NB);
    float* partb = (float*)((char*)d_ws + 512);            // 64*32*4096 f32 = 32 MB

    route_kernel<<<NB, 256, 0, stream>>>(x, gw, re0, re1, rpre);
    dim3 grid(NH, ND, NE);
    moe_gemv_kernel<<<grid, 256, 0, stream>>>(x, ew, re0, re1, rpre, partb);
    reduce_kernel<<<NB * HD / 4 / 128, 128, 0, stream>>>(partb, out);
}

// Round 8
// 99.933 us; speedup vs baseline: 1.4909x; 1.0613x over previous
//
#include <hip/hip_runtime.h>
#include <math.h>

// MoE top-2: S=1, B=32, H=4096, E=8.
// out[b][d] = sum_{e in top2(b)} wt[b][e] * sum_h x[b][h] * expert_w[e][h][d]
// Memory-bound: expert_w = 537 MB read once ~ 85 us @ 6.3 TB/s.
// R8: bf16 partial planes (halve partial r/w traffic; error budget 14x slack).
//     GEMV core = R4 depth-2 + R7 NT W-loads (proven 106 us).

constexpr int HD = 4096;
constexpr int NE = 8;
constexpr int NB = 32;
constexpr int TSLOT = 16;          // token slots per pass
constexpr int MAXTOK = 32;
constexpr int NH = 32;             // h segments
constexpr int HSEG = HD / NH;      // 128
constexpr int ND = 4;              // d chunks
constexpr int DCHUNK = HD / ND;    // 1024 floats
constexpr int NPART = 2 * NH;      // 64 partial planes per token

typedef float floatx4 __attribute__((ext_vector_type(4)));
typedef unsigned int uintx2 __attribute__((ext_vector_type(2)));

__device__ __forceinline__ float4 nt_load4(const float* p) {
    floatx4 v = __builtin_nontemporal_load((const floatx4*)p);
    return make_float4(v.x, v.y, v.z, v.w);
}

__device__ __forceinline__ unsigned int pack_bf16x2(float a, float b) {
    union { float f; unsigned int u; } ua, ub;
    ua.f = a; ub.f = b;
    unsigned int ra = (ua.u + 0x7FFFu + ((ua.u >> 16) & 1u)) >> 16;   // RNE
    unsigned int rb = (ub.u + 0x7FFFu + ((ub.u >> 16) & 1u)) >> 16;
    return ra | (rb << 16);
}

// ---- routing: 1 block per token: logits -> top-2 -------------------------
__global__ __launch_bounds__(256) void route_kernel(
    const float* __restrict__ x, const float* __restrict__ gw,
    int* __restrict__ re0, int* __restrict__ re1, float* __restrict__ rpre)
{
    const int b = blockIdx.x;
    const int tid = threadIdx.x;
    __shared__ float xrow[HD];

    const float4* xsrc = (const float4*)(x + (size_t)b * HD);
    #pragma unroll
    for (int i = 0; i < HD / 4 / 256; ++i) {
        int idx = i * 256 + tid;
        ((float4*)xrow)[idx] = xsrc[idx];
    }
    __syncthreads();

    const int e = tid & 7, hg = tid >> 3;
    float acc = 0.f;
    #pragma unroll 8
    for (int i = 0; i < HD / 32; ++i) {
        int h = hg + 32 * i;
        acc += xrow[h] * gw[h * NE + e];
    }
    __shared__ float part[32][NE];
    part[hg][e] = acc;
    __syncthreads();
    if (tid < NE) {
        float s = 0.f;
        #pragma unroll
        for (int i = 0; i < 32; ++i) s += part[i][tid];
        part[0][tid] = s;
    }
    __syncthreads();
    if (tid == 0) {
        float w0 = -3.4e38f; int e0 = 0;
        #pragma unroll
        for (int i = 0; i < NE; ++i) { float v = part[0][i]; if (v > w0) { w0 = v; e0 = i; } }
        float w1 = -3.4e38f; int e1 = 0;
        #pragma unroll
        for (int i = 0; i < NE; ++i) { if (i == e0) continue; float v = part[0][i]; if (v > w1) { w1 = v; e1 = i; } }
        float pre = 1.0f / (1.0f + expf(w1 - w0));
        re0[b] = e0; re1[b] = e1; rpre[b] = pre;
    }
}

// ---- grouped GEMV: block = (hseg, dchunk, e); all tokens of e ------------
__global__ __launch_bounds__(256, 4) void moe_gemv_kernel(
    const float* __restrict__ x, const float* __restrict__ ew,
    const int* __restrict__ re0, const int* __restrict__ re1,
    const float* __restrict__ rpre, unsigned short* __restrict__ part)
{
    const int hseg = blockIdx.x;        // 32
    const int dchunk = blockIdx.y;      // 4
    const int e = blockIdx.z;           // 8
    const int tid = threadIdx.x;

    __shared__ int   stok[MAXTOK];
    __shared__ int   sslt[MAXTOK];
    __shared__ float swt[MAXTOK];
    __shared__ int   snt;

    if (tid == 0) {
        int c = 0;
        for (int b = 0; b < NB; ++b) {
            int r0 = re0[b]; int r1 = re1[b]; float p = rpre[b];
            if (r0 == e)      { stok[c] = b; swt[c] = p;       sslt[c] = 0; ++c; }
            else if (r1 == e) { stok[c] = b; swt[c] = 1.f - p; sslt[c] = 1; ++c; }
        }
        snt = c;
        int cp = (c + TSLOT - 1) & ~(TSLOT - 1);
        for (int s = c; s < cp; ++s) { stok[s] = 0; swt[s] = 0.f; sslt[s] = 0; }
    }
    __syncthreads();
    const int nt = snt;
    if (nt == 0) return;
    const int npass = (nt + TSLOT - 1) / TSLOT;

    __shared__ float xs[HSEG][TSLOT];   // 8 KB, pre-scaled x
    const int h0 = hseg * HSEG;
    const int d0 = dchunk * DCHUNK + tid * 4;

    for (int p = 0; p < npass; ++p) {
        __syncthreads();
        {
            const int t = tid & 15, hb = tid >> 4;
            const int s = p * TSLOT + t;
            const int tok = stok[s]; const float wt = swt[s];
            const float* xp = x + (size_t)tok * HD + h0 + hb * 8;
            #pragma unroll
            for (int it = 0; it < 2; ++it) {
                float4 v = *(const float4*)(xp + it * 4);
                int h = hb * 8 + it * 4;
                xs[h + 0][t] = wt * v.x; xs[h + 1][t] = wt * v.y;
                xs[h + 2][t] = wt * v.z; xs[h + 3][t] = wt * v.w;
            }
        }
        __syncthreads();

        const float* wp = ew + (size_t)e * HD * HD + (size_t)h0 * HD + d0;

        float4 acc[TSLOT];              // 64 VGPRs
        #pragma unroll
        for (int t = 0; t < TSLOT; ++t) acc[t] = make_float4(0.f, 0.f, 0.f, 0.f);

        auto compute = [&](int h, const float4& wv) {
            #pragma unroll
            for (int q = 0; q < 4; ++q) {
                float4 xv = ((const float4*)(&xs[h][0]))[q];   // broadcast b128
                acc[q*4+0].x += xv.x * wv.x; acc[q*4+0].y += xv.x * wv.y;
                acc[q*4+0].z += xv.x * wv.z; acc[q*4+0].w += xv.x * wv.w;
                acc[q*4+1].x += xv.y * wv.x; acc[q*4+1].y += xv.y * wv.y;
                acc[q*4+1].z += xv.y * wv.z; acc[q*4+1].w += xv.y * wv.w;
                acc[q*4+2].x += xv.z * wv.x; acc[q*4+2].y += xv.z * wv.y;
                acc[q*4+2].z += xv.z * wv.z; acc[q*4+2].w += xv.z * wv.w;
                acc[q*4+3].x += xv.w * wv.x; acc[q*4+3].y += xv.w * wv.y;
                acc[q*4+3].z += xv.w * wv.z; acc[q*4+3].w += xv.w * wv.w;
            }
        };

        // 2-row software prefetch (R4 proven best); W read once -> nontemporal
        float4 wv0 = nt_load4(wp);
        float4 wv1 = nt_load4(wp + HD);
        wp += 2 * HD;
        for (int h = 0; h < HSEG - 2; h += 2) {
            float4 n0 = nt_load4(wp);
            float4 n1 = nt_load4(wp + HD);
            wp += 2 * HD;
            compute(h, wv0);
            compute(h + 1, wv1);
            wv0 = n0; wv1 = n1;
        }
        compute(HSEG - 2, wv0);
        compute(HSEG - 1, wv1);

        // bf16-packed coalesced stores to partial planes (no atomics)
        #pragma unroll
        for (int t = 0; t < TSLOT; ++t) {
            const int s = p * TSLOT + t;
            if (s < nt) {
                size_t off = ((size_t)(sslt[s] * NH + hseg) * NB + stok[s]) * HD + d0;
                uint2 pk;
                pk.x = pack_bf16x2(acc[t].x, acc[t].y);
                pk.y = pack_bf16x2(acc[t].z, acc[t].w);
                *(uint2*)(part + off) = pk;
            }
        }
    }
}

// ---- reduce: out[b][d] = sum over 64 bf16 partial planes -----------------
__global__ __launch_bounds__(128) void reduce_kernel(
    const unsigned short* __restrict__ part, float* __restrict__ out)
{
    const int idx = blockIdx.x * 128 + threadIdx.x;    // float4 index, 32768
    constexpr size_t PSTRIDE = (size_t)NB * HD;        // elems per plane
    float4 s = make_float4(0.f, 0.f, 0.f, 0.f);
    #pragma unroll 8
    for (int j = 0; j < NPART; ++j) {
        uintx2 v = __builtin_nontemporal_load(
            (const uintx2*)(part + (size_t)j * PSTRIDE + (size_t)idx * 4));
        union { unsigned int u; float f; } a, b, c, d;
        a.u = v.x << 16;          b.u = v.x & 0xFFFF0000u;
        c.u = v.y << 16;          d.u = v.y & 0xFFFF0000u;
        s.x += a.f; s.y += b.f; s.z += c.f; s.w += d.f;
    }
    ((float4*)out)[idx] = s;
}

extern "C" void kernel_launch(void* const* d_in, const int* in_sizes, int n_in,
                              void* d_out, int out_size, void* d_ws, size_t ws_size,
                              hipStream_t stream) {
    const float* x  = (const float*)d_in[0];   // [1,1,32,4096]
    const float* gw = (const float*)d_in[1];   // [4096,8]
    const float* ew = (const float*)d_in[2];   // [8,4096,4096]
    float* out = (float*)d_out;                // [1,1,32,4096] fp32

    int*   re0  = (int*)d_ws;
    int*   re1  = re0 + NB;
    float* rpre = (float*)(re1 + NB);
    unsigned short* partb = (unsigned short*)((char*)d_ws + 512);  // 64*32*4096 bf16 = 16 MB

    route_kernel<<<NB, 256, 0, stream>>>(x, gw, re0, re1, rpre);
    dim3 grid(NH, ND, NE);
    moe_gemv_kernel<<<grid, 256, 0, stream>>>(x, ew, re0, re1, rpre, partb);
    reduce_kernel<<<NB * HD / 4 / 128, 128, 0, stream>>>(partb, out);
}